// Round 1
// baseline (1963.526 us; speedup 1.0000x reference)
//
#include <hip/hip_runtime.h>

#define DEVFN static __device__ __forceinline__

typedef __attribute__((ext_vector_type(8))) short short8;
typedef __attribute__((ext_vector_type(4))) float f32x4;

// ---------- bf16 helpers (raw ushort storage) ----------
DEVFN unsigned short f2bf(float f) {
    union { float f; unsigned u; } a; a.f = f;
    unsigned u = a.u;
    unsigned r = (u + 0x7FFFu + ((u >> 16) & 1u)) >> 16;   // RNE
    return (unsigned short)r;
}
DEVFN float bf2f(unsigned short b) {
    union { unsigned u; float f; } a; a.u = ((unsigned)b) << 16;
    return a.f;
}
DEVFN float2 bfpair(unsigned v) {
    float2 r;
    union { unsigned u; float f; } a;
    a.u = (v & 0xFFFFu) << 16; r.x = a.f;
    a.u = v & 0xFFFF0000u;     r.y = a.f;
    return r;
}

// ---------- async global->LDS (16B per lane, wave-uniform LDS base) ----------
DEVFN void gload16(const void* g, void* lds) {
    __builtin_amdgcn_global_load_lds(
        (const __attribute__((address_space(1))) unsigned int*)g,
        (__attribute__((address_space(3))) unsigned int*)lds, 16, 0, 0);
}

// ---------- prep: xs = [x | rwkv] cast bf16 ----------
__global__ __launch_bounds__(256) void pack_xs_kernel(
        const float* __restrict__ x, const float* __restrict__ r,
        unsigned short* __restrict__ xs) {
    int i = blockIdx.x * 256 + threadIdx.x;      // 4-float chunk, total 4096*4096/4
    int n  = i >> 10;                            // 1024 chunks per row
    int cw = i & 1023;
    const float* src = (cw < 512) ? (x + (size_t)n * 2048 + cw * 4)
                                  : (r + (size_t)n * 2048 + (cw - 512) * 4);
    float4 v = *(const float4*)src;
    ushort4 o;
    o.x = f2bf(v.x); o.y = f2bf(v.y); o.z = f2bf(v.z); o.w = f2bf(v.w);
    *(ushort4*)(xs + (size_t)n * 4096 + cw * 4) = o;
}

// ---------- prep: transpose + cast fp32[R][Cc] -> bf16[Cc][R] ----------
__global__ __launch_bounds__(256) void transpose_cast_kernel(
        const float* __restrict__ in, unsigned short* __restrict__ out,
        int R, int Cc) {
    __shared__ float tile[32][33];
    int tx = threadIdx.x & 31, ty = threadIdx.x >> 5;   // 32 x 8
    int tr = blockIdx.y * 32, tc = blockIdx.x * 32;
#pragma unroll
    for (int i = 0; i < 4; i++) {
        int rr = ty + i * 8;
        tile[rr][tx] = in[(size_t)(tr + rr) * Cc + tc + tx];
    }
    __syncthreads();
#pragma unroll
    for (int i = 0; i < 4; i++) {
        int rr = ty + i * 8;
        out[(size_t)(tc + rr) * R + tr + tx] = f2bf(tile[tx][rr]);
    }
}

// ---------- GEMM: C[M,N] = A[M,K](bf16,row) * Bt[N,K](bf16,row)^T ----------
// 128x128 tile, BK=32, 4 waves (2x2), 16x16x32 bf16 MFMA, m97-style staging.
// EPI: 0 = store bf16; 1 = sigmoid(acc + aux_f32[col]) bf16;
//      2 = loss: sum((acc - aux_f32[row*ldc+col])^2) -> atomicAdd(loss_accum);
//      3 = store fp32 acc * bf2f(aux_bf16[row*ldc+col])
template <int EPI>
__global__ __launch_bounds__(256) void gemm_bt(
        const unsigned short* __restrict__ A, int lda,
        const unsigned short* __restrict__ Bt, int ldb,
        void* __restrict__ Cptr, int ldc, int K,
        const float* __restrict__ aux_f32,
        const unsigned short* __restrict__ aux_bf16,
        float* __restrict__ loss_accum) {
    __shared__ __align__(16) unsigned short Atile[128 * 32];
    __shared__ __align__(16) unsigned short Btile[128 * 32];
    const int tid  = threadIdx.x;
    const int wave = tid >> 6, lane = tid & 63;
    const int brow = blockIdx.y << 7, bcol = blockIdx.x << 7;
    const int wr = (wave >> 1) & 1, wc = wave & 1;

    f32x4 acc[4][4] = {};

    // staging: chunk c = wave*2 + i covers LDS bytes [c*1024, c*1024+1024)
    // lane covers 16B at row (c*16 + lane/4), byte-col (lane&3)*16
    const int rA = wave * 32 + (lane >> 2);          // row for i=0 (c = wave*2)
    const int ce = (lane & 3) * 8;                   // elem col offset (16B = 8 bf16)
    const unsigned short* aSrc = A  + (size_t)(brow + rA) * lda + ce;
    const unsigned short* bSrc = Bt + (size_t)(bcol + rA) * ldb + ce;
    unsigned short* aDst = &Atile[wave * 1024];      // c*512 elems, c = wave*2
    unsigned short* bDst = &Btile[wave * 1024];

    for (int kt = 0; kt < K; kt += 32) {
        gload16(aSrc + kt,            aDst);
        gload16(aSrc + 16 * lda + kt, aDst + 512);
        gload16(bSrc + kt,            bDst);
        gload16(bSrc + 16 * ldb + kt, bDst + 512);
        __syncthreads();   // compiler drains vmcnt before s_barrier

        short8 afr[4], bfr[4];
        const int kgr = (lane >> 4) * 8;
#pragma unroll
        for (int m = 0; m < 4; m++)
            afr[m] = *(const short8*)&Atile[(wr * 64 + m * 16 + (lane & 15)) * 32 + kgr];
#pragma unroll
        for (int n = 0; n < 4; n++)
            bfr[n] = *(const short8*)&Btile[(wc * 64 + n * 16 + (lane & 15)) * 32 + kgr];
#pragma unroll
        for (int m = 0; m < 4; m++)
#pragma unroll
            for (int n = 0; n < 4; n++)
                acc[m][n] = __builtin_amdgcn_mfma_f32_16x16x32_bf16(
                    afr[m], bfr[n], acc[m][n], 0, 0, 0);
        __syncthreads();
    }

    // epilogue: C/D layout (verified): col = lane&15, row = (lane>>4)*4 + reg
    const int rl = (lane >> 4) * 4;
    const int cl = lane & 15;
    const int row0 = brow + wr * 64;
    const int col0 = bcol + wc * 64;

    if constexpr (EPI == 2) {
        float lsum = 0.f;
#pragma unroll
        for (int m = 0; m < 4; m++)
#pragma unroll
            for (int n = 0; n < 4; n++)
#pragma unroll
                for (int rg = 0; rg < 4; rg++) {
                    int gr = row0 + m * 16 + rl + rg;
                    int gc = col0 + n * 16 + cl;
                    float d = acc[m][n][rg] - aux_f32[(size_t)gr * ldc + gc];
                    lsum += d * d;
                }
#pragma unroll
        for (int msk = 1; msk < 64; msk <<= 1)
            lsum += __shfl_xor(lsum, msk, 64);
        if (lane == 0) atomicAdd(loss_accum, lsum);
        return;
    }

#pragma unroll
    for (int m = 0; m < 4; m++)
#pragma unroll
        for (int n = 0; n < 4; n++)
#pragma unroll
            for (int rg = 0; rg < 4; rg++) {
                int gr = row0 + m * 16 + rl + rg;
                int gc = col0 + n * 16 + cl;
                size_t idx = (size_t)gr * ldc + gc;
                if constexpr (EPI == 0) {
                    ((unsigned short*)Cptr)[idx] = f2bf(acc[m][n][rg]);
                } else if constexpr (EPI == 1) {
                    float t = acc[m][n][rg] + aux_f32[gc];
                    ((unsigned short*)Cptr)[idx] = f2bf(1.f / (1.f + expf(-t)));
                } else {  // EPI == 3
                    float gv = bf2f(aux_bf16[idx]);
                    ((float*)Cptr)[idx] = acc[m][n][rg] * gv;
                }
            }
}

// ---------- pmean[n][c] = mean_p prefix[n][p*2048 + c] ----------
__global__ __launch_bounds__(256) void pmean_kernel(
        const unsigned short* __restrict__ prefix, unsigned short* __restrict__ pm) {
    int i  = blockIdx.x * 256 + threadIdx.x;   // 8-elem chunk, total 4096*2048/8
    int n  = i >> 8;                           // 256 chunks per row
    int c8 = (i & 255) * 8;
    float acc[8] = {0, 0, 0, 0, 0, 0, 0, 0};
#pragma unroll
    for (int p = 0; p < 8; p++) {
        const unsigned short* src = prefix + (size_t)n * 16384 + p * 2048 + c8;
        uint4 raw = *(const uint4*)src;
        unsigned w[4] = {raw.x, raw.y, raw.z, raw.w};
#pragma unroll
        for (int j = 0; j < 4; j++) {
            float2 fp = bfpair(w[j]);
            acc[2 * j] += fp.x; acc[2 * j + 1] += fp.y;
        }
    }
    uint4 o;
    unsigned* ow = (unsigned*)&o;
#pragma unroll
    for (int j = 0; j < 4; j++)
        ow[j] = (unsigned)f2bf(acc[2 * j] * 0.125f) |
                ((unsigned)f2bf(acc[2 * j + 1] * 0.125f) << 16);
    *(uint4*)(pm + (size_t)n * 2048 + c8) = o;
}

// ---------- attention: one wave per (n,h), P=8 keys, D=128 ----------
__global__ __launch_bounds__(256) void attn_kernel(
        const unsigned short* __restrict__ q, const unsigned short* __restrict__ k,
        const unsigned short* __restrict__ v, unsigned short* __restrict__ o) {
    int gw   = (blockIdx.x * 256 + threadIdx.x) >> 6;  // n*16 + h
    int lane = threadIdx.x & 63;
    int n = gw >> 4, h = gw & 15;
    size_t qoff = (size_t)n * 2048 + h * 128 + lane * 2;
    float2 qv = bfpair(*(const unsigned*)(q + qoff));
    float s[8];
#pragma unroll
    for (int p = 0; p < 8; p++) {
        size_t koff = (size_t)(n * 8 + p) * 2048 + h * 128 + lane * 2;
        float2 kv = bfpair(*(const unsigned*)(k + koff));
        float d = qv.x * kv.x + qv.y * kv.y;
#pragma unroll
        for (int msk = 1; msk < 64; msk <<= 1) d += __shfl_xor(d, msk, 64);
        s[p] = d * 0.08838834764831845f;   // 1/sqrt(128)
    }
    float mx = s[0];
#pragma unroll
    for (int p = 1; p < 8; p++) mx = fmaxf(mx, s[p]);
    float e[8], den = 0.f;
#pragma unroll
    for (int p = 0; p < 8; p++) { e[p] = expf(s[p] - mx); den += e[p]; }
    float inv = 1.f / den;
    float o0 = 0.f, o1 = 0.f;
#pragma unroll
    for (int p = 0; p < 8; p++) {
        size_t voff = (size_t)(n * 8 + p) * 2048 + h * 128 + lane * 2;
        float2 vv = bfpair(*(const unsigned*)(v + voff));
        float a = e[p] * inv;
        o0 += a * vv.x; o1 += a * vv.y;
    }
    *(unsigned*)(o + qoff) = (unsigned)f2bf(o0) | ((unsigned)f2bf(o1) << 16);
}

__global__ __launch_bounds__(64) void finalize_loss_kernel(
        const float* __restrict__ accum, float* __restrict__ dst) {
    if (threadIdx.x == 0) dst[0] = accum[0] * (1.0f / (4096.0f * 2048.0f));
}

// ---------- launch ----------
extern "C" void kernel_launch(void* const* d_in, const int* in_sizes, int n_in,
                              void* d_out, int out_size, void* d_ws, size_t ws_size,
                              hipStream_t stream) {
    const float* x    = (const float*)d_in[0];
    const float* rwkv = (const float*)d_in[1];
    const float* Wq   = (const float*)d_in[2];
    const float* Wk   = (const float*)d_in[3];
    const float* Wv   = (const float*)d_in[4];
    const float* Wo   = (const float*)d_in[5];
    const float* Wg   = (const float*)d_in[6];
    const float* bg   = (const float*)d_in[7];
    const float* Wb   = (const float*)d_in[8];
    const float* Wr   = (const float*)d_in[9];
    float* out = (float*)d_out;
    char*  ws  = (char*)d_ws;

    unsigned short* xs     = (unsigned short*)(ws + 0ull);            // 33,554,432 B
    unsigned short* wbT    = (unsigned short*)(ws + 33554432ull);     // 134,217,728 B (reused as kbuf)
    unsigned short* wqT    = (unsigned short*)(ws + 167772160ull);    // 8,388,608 B each
    unsigned short* wkT    = (unsigned short*)(ws + 176160768ull);
    unsigned short* wvT    = (unsigned short*)(ws + 184549376ull);
    unsigned short* wgT    = (unsigned short*)(ws + 192937984ull);
    unsigned short* wrT    = (unsigned short*)(ws + 201326592ull);
    unsigned short* woT    = (unsigned short*)(ws + 209715200ull);
    unsigned short* prefix = (unsigned short*)(ws + 218103808ull);    // 134,217,728 B
    unsigned short* vbuf   = (unsigned short*)(ws + 352321536ull);    // 134,217,728 B
    unsigned short* qbuf   = (unsigned short*)(ws + 486539264ull);    // 16,777,216 B
    unsigned short* gbuf   = (unsigned short*)(ws + 503316480ull);
    unsigned short* pmean  = (unsigned short*)(ws + 520093696ull);
    unsigned short* attno  = (unsigned short*)(ws + 536870912ull);
    float*          lossA  = (float*)(ws + 553648128ull);
    unsigned short* kbuf   = wbT;   // WbT dead after bridge GEMM

    hipMemsetAsync(lossA, 0, 16, stream);

    pack_xs_kernel<<<16384, 256, 0, stream>>>(x, rwkv, xs);
    transpose_cast_kernel<<<dim3(512, 128), 256, 0, stream>>>(Wb, wbT, 4096, 16384);
    transpose_cast_kernel<<<dim3(64, 64),  256, 0, stream>>>(Wq, wqT, 2048, 2048);
    transpose_cast_kernel<<<dim3(64, 64),  256, 0, stream>>>(Wk, wkT, 2048, 2048);
    transpose_cast_kernel<<<dim3(64, 64),  256, 0, stream>>>(Wv, wvT, 2048, 2048);
    transpose_cast_kernel<<<dim3(64, 64),  256, 0, stream>>>(Wg, wgT, 2048, 2048);
    transpose_cast_kernel<<<dim3(64, 64),  256, 0, stream>>>(Wr, wrT, 2048, 2048);
    transpose_cast_kernel<<<dim3(64, 64),  256, 0, stream>>>(Wo, woT, 2048, 2048);

    // prefix = xs @ Wb          [4096,16384], K=4096
    gemm_bt<0><<<dim3(128, 32), 256, 0, stream>>>(xs, 4096, wbT, 4096,
        prefix, 16384, 4096, nullptr, nullptr, nullptr);
    // k = prefix @ Wk           [32768,2048], K=2048   (writes over WbT region)
    gemm_bt<0><<<dim3(16, 256), 256, 0, stream>>>(prefix, 2048, wkT, 2048,
        kbuf, 2048, 2048, nullptr, nullptr, nullptr);
    // v = prefix @ Wv
    gemm_bt<0><<<dim3(16, 256), 256, 0, stream>>>(prefix, 2048, wvT, 2048,
        vbuf, 2048, 2048, nullptr, nullptr, nullptr);
    // pmean = mean_p(prefix)
    pmean_kernel<<<4096, 256, 0, stream>>>(prefix, pmean);
    // q = x @ Wq   (x = first 2048 cols of xs, lda=4096)
    gemm_bt<0><<<dim3(16, 32), 256, 0, stream>>>(xs, 4096, wqT, 2048,
        qbuf, 2048, 2048, nullptr, nullptr, nullptr);
    // g = sigmoid(x @ Wg + bg)
    gemm_bt<1><<<dim3(16, 32), 256, 0, stream>>>(xs, 4096, wgT, 2048,
        gbuf, 2048, 2048, bg, nullptr, nullptr);
    // recon loss: sum((pmean @ Wr - x)^2)
    gemm_bt<2><<<dim3(16, 32), 256, 0, stream>>>(pmean, 2048, wrT, 2048,
        nullptr, 2048, 2048, x, nullptr, lossA);
    // attention
    attn_kernel<<<16384, 256, 0, stream>>>(qbuf, kbuf, vbuf, attno);
    // out = (attno @ Wo) * g    -> fp32 d_out
    gemm_bt<3><<<dim3(16, 32), 256, 0, stream>>>(attno, 2048, woT, 2048,
        out, 2048, 2048, nullptr, gbuf, nullptr);

    finalize_loss_kernel<<<1, 64, 0, stream>>>(lossA, out + 8388608);
}